// Round 10
// baseline (329.895 us; speedup 1.0000x reference)
//
#include <hip/hip_runtime.h>
#include <hip/hip_fp16.h>
#include <hip/hip_cooperative_groups.h>

namespace cg = cooperative_groups;

// Problem constants (fixed by the reference)
constexpr int L = 64;     // sites
constexpr int P = 4;      // physical dim
constexpr int D = 128;    // bond dim
constexpr int B = 2048;   // batch
constexpr int EPW = 16;   // batch elements per WG (one mfma M-tile)

using v8h = __attribute__((ext_vector_type(8))) _Float16;  // mfma A/B frag
using v4h = __attribute__((ext_vector_type(4))) _Float16;
using v4f = __attribute__((ext_vector_type(4))) float;     // mfma C/D frag

// ---- workspace layout (bytes); TOTAL 10 MB ------------------------------
constexpr size_t UT_OFF  = 0;               // u_t fp32 [d][b]   1 MB
constexpr size_t WT_OFF  = 1048576;         // w_t fp32 [d][b]   1 MB
constexpr size_t MTF_OFF = 2097152;         // sites 0..31  fp16 [mat][c][d] 4 MB
constexpr size_t MTB_OFF = 6291456;         // sites 32..63 fp16 [mat][d][c] 4 MB

// ---- chain-phase LDS map (bytes) ----------------------------------------
constexpr int VLDS0 = 131072;
constexpr int VLDS1 = 131072 + 4096;
constexpr int PLDS  = 131072 + 8192;
constexpr int SMEM_BYTES = PLDS + L * EPW * 4;  // 143360 -> 1 WG/CU, 8 waves

// s_waitcnt immediates (gfx9: vmcnt[3:0] | exp<<4 | lgkm<<8 | vmcnt[5:4]<<14)
#define WAIT_VM8   0xF78   // vmcnt(8) — drain all but the newest 8 loads
#define WAIT_VM0   0xF70   // vmcnt(0)
#define WAIT_LGKM0 0xC07F  // lgkmcnt(0) only; vmcnt untouched

__device__ __forceinline__ void gl2lds16(const void* g, void* l) {
  __builtin_amdgcn_global_load_lds(
      (const __attribute__((address_space(1))) void*)g,
      (__attribute__((address_space(3))) void*)l, 16, 0, 0);
}

// ---------------------------------------------------------------------------
// ONE cooperative kernel, 256 WGs x 512 threads (1 WG/CU, exactly resident):
//  phase A: convert fp32 [site][p][d][c] ->
//           sites 32..63: mtb row-major fp16 [d][c]  (bwd B-frags)
//           sites  0..31: mtf transposed fp16 [c][d] (fwd B-frags) —
//           register transpose (R9-verified), 1 matrix/WG, 512 threads
//  grid.sync()
//  phase B: half-chain (R7/R9-verified verbatim): even blockIdx = fwd
//           (sites 0..31 ascending, u = l^T prod M), odd = bwd (sites
//           63..32 descending, w = prod M r; same GEMM via mtb).
//           Sync: site boundary __syncthreads; lgkmcnt(0) fence before
//           DMA-writing a buffer whose ds_reads may still be queued (the
//           R4-R6 cross-pipe hazard); vmcnt(8) before h=1 consume.
//           Frag layouts: A[m=lane&15][k=q4*8+j], B^T[n=lane&15][k=q4*8+j],
//           C[row=q4*4+r][col=lane&15]. Chunk LDS [p][c16][kseg8] 16B units,
//           kseg slot ^= (c&7); inverse swizzle baked into global address.
//  grid.sync()
//  phase C: combine amp[b] = sum_d u[d][b] w[d][b], 4 WGs, coalesced.
// Fusing deletes 2 kernel launches + inter-dispatch drain gaps (R9: ~75 us
// of the 132 total was outside the chain dispatch).
// ---------------------------------------------------------------------------
__global__ __launch_bounds__(512, 1) void mps_fused(
    const float* __restrict__ src, const int* __restrict__ onstate,
    const float* __restrict__ left_vec, const float* __restrict__ right_vec,
    float* __restrict__ out, char* __restrict__ ws) {
  float*    ut  = (float*)(ws + UT_OFF);
  float*    wt  = (float*)(ws + WT_OFF);
  _Float16* mtf = (_Float16*)(ws + MTF_OFF);
  _Float16* mtb = (_Float16*)(ws + MTB_OFF);

  extern __shared__ char smem[];
  const int tid = threadIdx.x;
  const int wave = tid >> 6, lane = tid & 63;
  const int me = lane & 15, q4 = lane >> 4;

  // ======== phase A: convert (1 matrix per WG, 512 threads) ========
  {
    const int mat = blockIdx.x;       // site*P + p
    const int site = mat >> 2;
    if (site >= 32) {                 // bwd half: straight cast, keep [d][c]
      const float4* sb = (const float4*)(src + (size_t)mat * 16384);
      _Float16* bb = mtb + (size_t)(mat - 128) * 16384;
#pragma unroll
      for (int it = 0; it < 8; ++it) {
        int idx = tid + it * 512;     // 4096 float4 per matrix
        float4 f = sb[idx];
        v4h h4 = {(_Float16)f.x, (_Float16)f.y, (_Float16)f.z, (_Float16)f.w};
        *(v4h*)(bb + idx * 4) = h4;
      }
    } else {                          // fwd half: register transpose
      const float* sb = src + (size_t)mat * 16384;
      _Float16* fb = mtf + (size_t)mat * 16384;
      const int cl = tid & 63;        // c within 64-lane run (coalesced)
      const int dg = tid >> 6;        // d8 group 0..7
#pragma unroll
      for (int ch = 0; ch < 2; ++ch) {
        const int c = ch * 64 + cl;
#pragma unroll
        for (int dh = 0; dh < 2; ++dh) {
          const int d8 = dh * 8 + dg;
          v8h v;
#pragma unroll
          for (int j = 0; j < 8; ++j) v[j] = (_Float16)sb[(d8 * 8 + j) * D + c];
          *(v8h*)(fb + c * D + d8 * 8) = v;
        }
      }
    }
  }
  __threadfence();                    // device-scope: cross-XCD visibility
  cg::this_grid().sync();

  // ======== phase B: half-chain (R7/R9 verbatim) ========
  const bool fwd = !(blockIdx.x & 1);
  const int b0 = (blockIdx.x >> 1) * EPW;
  const _Float16* mbase = fwd ? mtf : mtb;   // my half's 128 matrices
  const float* ivec = fwd ? left_vec : right_vec;
  float* ovec = fwd ? ut : wt;

  // ---- stage onstate -> plds[site][e] (global site index)
  int* plds = (int*)(smem + PLDS);
#pragma unroll
  for (int j = 0; j < 2; ++j) {
    int idx = tid + j * 512;
    int e = idx >> 6, i = idx & 63;
    plds[i * EPW + e] = onstate[(b0 + e) * L + i];
  }
  // ---- init v = ivec for every element (swizzled fp16)
  if (tid < 256) {
    int e = tid >> 4, seg = tid & 15;
    _Float16* vp = (_Float16*)(smem + VLDS0) + e * 128 + (seg ^ (e & 7)) * 8;
#pragma unroll
    for (int j = 0; j < 8; ++j) vp[j] = (_Float16)ivec[seg * 8 + j];
  }

  char* wbuf = smem + wave * 16384;   // my private 2 x 8 KB chunk buffers

  // per-lane, site-invariant staging source offsets (inverse swizzle baked)
  int soff[8];
#pragma unroll
  for (int i = 0; i < 8; ++i) {
    int u = i * 64 + lane;
    int p = u >> 7, r = u & 127, cl = r >> 3, slot = r & 7;
    soff[i] = p * 32768 + (wave * 16 + cl) * 256 + (slot ^ (cl & 7)) * 16;
  }
  auto stage = [&](int ls, int h, int z) {
    const char* gb = (const char*)mbase + (size_t)ls * 131072 + h * 128;
    char* lb = wbuf + z * 8192;
#pragma unroll
    for (int i = 0; i < 8; ++i) gl2lds16(gb + soff[i], lb + i * 1024);
  };
  auto consume = [&](int h, int z, int pm, const char* vb, v4f& acc) {
    const int s0 = h * 8 + q4, s1 = h * 8 + 4 + q4;
    v8h a0 = *(const v8h*)(vb + me * 256 + (s0 ^ (me & 7)) * 16);
    v8h a1 = *(const v8h*)(vb + me * 256 + (s1 ^ (me & 7)) * 16);
    const char* cb = wbuf + z * 8192;
#pragma unroll
    for (int p = 0; p < P; ++p) {
      const bool isp = (pm == p);
      v8h zf = {};
      v8h am0 = isp ? a0 : zf;
      v8h am1 = isp ? a1 : zf;
      const char* pb = cb + p * 2048 + me * 128;
      v8h bf0 = *(const v8h*)(pb + ((q4) ^ (me & 7)) * 16);
      v8h bf1 = *(const v8h*)(pb + ((4 + q4) ^ (me & 7)) * 16);
      acc = __builtin_amdgcn_mfma_f32_16x16x32_f16(am0, bf0, acc, 0, 0, 0);
      acc = __builtin_amdgcn_mfma_f32_16x16x32_f16(am1, bf1, acc, 0, 0, 0);
    }
  };

  stage(fwd ? 0 : 31, 0, 0);          // prologue: chunk g=0 -> buf0
  __syncthreads();                    // drains everything (incl. prologue)

  const int c0 = wave * 16 + me;      // my output column
  v4f accL = {0.f, 0.f, 0.f, 0.f};
  for (int site = 0; site < 32; ++site) {
    const int site_g = fwd ? site : 63 - site;   // global site (plds index)
    const int ls     = fwd ? site : 31 - site;   // local site in my half
    const int pm = plds[site_g * EPW + me];
    const char* vb = smem + ((site & 1) ? VLDS1 : VLDS0);
    v4f acc = {0.f, 0.f, 0.f, 0.f};

    // ---- h = 0: issue (ls, h=1) -> buf1; consume buf0 (barrier-drained)
    stage(ls, 1, 1);
    consume(0, 0, pm, vb, acc);

    // ---- h = 1
    if (site < 31) {
      const int lsn = fwd ? site + 1 : 30 - site;
      // hazard fence: drain my LDS-pipe reads of buf0 before DMA-writing it
      __builtin_amdgcn_sched_barrier(0);
      __builtin_amdgcn_s_waitcnt(WAIT_LGKM0);
      __builtin_amdgcn_sched_barrier(0);
      stage(lsn, 0, 0);                         // prefetch next site -> buf0
      __builtin_amdgcn_s_waitcnt(WAIT_VM8);     // drain buf1 only
      consume(1, 1, pm, vb, acc);
      // v-exchange: write v_new fp16 (C-layout rows) to the other buffer
      _Float16* vn = (_Float16*)(smem + ((site & 1) ? VLDS0 : VLDS1));
#pragma unroll
      for (int r = 0; r < 4; ++r) {
        int e = q4 * 4 + r;
        vn[e * 128 + ((c0 >> 3) ^ (e & 7)) * 8 + (c0 & 7)] = (_Float16)acc[r];
      }
      __syncthreads();
    } else {
      __builtin_amdgcn_s_waitcnt(WAIT_VM0);     // last chunk: full drain
      consume(1, 1, pm, vb, acc);
      accL = acc;
    }
  }
  // half-chain epilogue: store transposed [d][b] (fp32)
#pragma unroll
  for (int r = 0; r < 4; ++r) ovec[c0 * B + b0 + q4 * 4 + r] = accL[r];

  __threadfence();                    // device-scope: cross-XCD visibility
  cg::this_grid().sync();

  // ======== phase C: combine (4 WGs, coalesced along b) ========
  if (blockIdx.x < 4) {
    const int b = blockIdx.x * 512 + tid;
    float s = 0.f;
#pragma unroll 8
    for (int d = 0; d < D; ++d) s += ut[d * B + b] * wt[d * B + b];
    out[b] = s;
  }
}

// ---------------------------------------------------------------------------
extern "C" void kernel_launch(void* const* d_in, const int* in_sizes, int n_in,
                              void* d_out, int out_size, void* d_ws,
                              size_t ws_size, hipStream_t stream) {
  const int*   onstate      = (const int*)d_in[0];
  const float* site_tensors = (const float*)d_in[1];
  const float* left_vec     = (const float*)d_in[2];
  const float* right_vec    = (const float*)d_in[3];
  float*       out          = (float*)d_out;
  char*        ws           = (char*)d_ws;   // needs 10 MB

  hipFuncSetAttribute((const void*)mps_fused,
                      hipFuncAttributeMaxDynamicSharedMemorySize, SMEM_BYTES);

  void* args[] = {(void*)&site_tensors, (void*)&onstate, (void*)&left_vec,
                  (void*)&right_vec,    (void*)&out,     (void*)&ws};
  hipLaunchCooperativeKernel((const void*)mps_fused, dim3(256), dim3(512),
                             args, SMEM_BYTES, stream);
}

// Round 11
// 132.568 us; speedup vs baseline: 2.4885x; 2.4885x over previous
//
#include <hip/hip_runtime.h>
#include <hip/hip_fp16.h>

// Problem constants (fixed by the reference)
constexpr int L = 64;     // sites
constexpr int P = 4;      // physical dim
constexpr int D = 128;    // bond dim
constexpr int B = 2048;   // batch
constexpr int EPW = 16;   // batch elements per WG (one mfma M-tile)
constexpr int NG = B / EPW;   // 128 batch groups -> 256 WGs (fwd+bwd)

using v8h = __attribute__((ext_vector_type(8))) _Float16;  // mfma A/B frag
using v4h = __attribute__((ext_vector_type(4))) _Float16;
using v4f = __attribute__((ext_vector_type(4))) float;     // mfma C/D frag

// ---- workspace layout (bytes); TOTAL 10 MB (same proven budget as R9) ---
constexpr size_t UT_OFF  = 0;               // u_t fp16 [d][b]   512 KB
constexpr size_t WT_OFF  = 524288;          // w_t fp16 [d][b]   512 KB
constexpr size_t FLG_OFF = 1048576;         // pair flags, 128 x 2 u32
constexpr size_t MTF_OFF = 2097152;         // sites 0..31  fp16 [mat][c][d] 4 MB
constexpr size_t MTB_OFF = 6291456;         // sites 32..63 fp16 [mat][d][c] 4 MB

// ---- chain-kernel LDS map (bytes) ---------------------------------------
constexpr int VLDS0 = 131072;
constexpr int VLDS1 = 131072 + 4096;
constexpr int PLDS  = 131072 + 8192;
constexpr int SMEM_BYTES = PLDS + L * EPW * 4;  // 143360 -> 1 WG/CU, 8 waves

// s_waitcnt immediates (gfx9: vmcnt[3:0] | exp<<4 | lgkm<<8 | vmcnt[5:4]<<14)
#define WAIT_VM8   0xF78   // vmcnt(8) — drain all but the newest 8 loads
#define WAIT_VM0   0xF70   // vmcnt(0)
#define WAIT_LGKM0 0xC07F  // lgkmcnt(0) only; vmcnt untouched

#define FLAG_MAGIC 0x13579BDFu  // != 0x0 and != 0xAAAAAAAA poison

__device__ __forceinline__ void gl2lds16(const void* g, void* l) {
  __builtin_amdgcn_global_load_lds(
      (const __attribute__((address_space(1))) void*)g,
      (__attribute__((address_space(3))) void*)l, 16, 0, 0);
}

// ---------------------------------------------------------------------------
// Convert fp32 [site][p][d][c] (R9-verified verbatim):
//   sites 32..63 -> mtb, row-major fp16 [d][c]  (bwd B-frags) — straight cast
//   sites  0..31 -> mtf, transposed fp16 [c][d] (fwd B-frags) — register
//   transpose (8 coalesced column loads -> one v8h store; no LDS, no banks).
// ---------------------------------------------------------------------------
__global__ void convert_dual(const float* __restrict__ src,
                             _Float16* __restrict__ mtf,
                             _Float16* __restrict__ mtb) {
  const int mat = blockIdx.x;         // site*P + p
  const int site = mat >> 2;
  const int t = threadIdx.x;
  if (site >= 32) {                   // bwd half: straight cast, keep [d][c]
    const float4* sb = (const float4*)(src + (size_t)mat * 16384);
    _Float16* bb = mtb + (size_t)(mat - 128) * 16384;
#pragma unroll
    for (int it = 0; it < 16; ++it) {
      int idx = t + it * 256;         // 4096 float4 per matrix
      float4 f = sb[idx];
      v4h h4 = {(_Float16)f.x, (_Float16)f.y, (_Float16)f.z, (_Float16)f.w};
      *(v4h*)(bb + idx * 4) = h4;
    }
    return;
  }
  // fwd half: register transpose
  const float* sb = src + (size_t)mat * 16384;
  _Float16* fb = mtf + (size_t)mat * 16384;
  const int cl = t & 63;              // c within 64-lane run (coalesced dim)
  const int dg = t >> 6;              // d8 group 0..3
#pragma unroll
  for (int ch = 0; ch < 2; ++ch) {    // c halves
    const int c = ch * 64 + cl;
#pragma unroll
    for (int dh = 0; dh < 4; ++dh) {  // d8 = dh*4 + dg
      const int d8 = dh * 4 + dg;
      v8h v;
#pragma unroll
      for (int j = 0; j < 8; ++j) v[j] = (_Float16)sb[(d8 * 8 + j) * D + c];
      *(v8h*)(fb + c * D + d8 * 8) = v;
    }
  }
}

// ---------------------------------------------------------------------------
// Half-chain + fused combine: 256 WGs x 8 waves x 16 elements; even
// blockIdx = fwd (sites 0..31 ascending, u = l^T prod M), odd = bwd (sites
// 63..32 descending, w = prod M r; same GEMM via row-major mtb).
//
// R11 sync discipline (AITER-style; vmcnt never drains to 0 in steady
// state — R9's __syncthreads forcibly completed the cross-site prefetch at
// every site boundary):
//  - consume(h=0): explicit vmcnt(8) — outstanding = prev-site buf0 (8,
//    oldest) + this-site buf1 (8, newest); drains exactly buf0.
//  - before DMA-writing buf0 at h=1: lgkmcnt(0) fence (cross-pipe hazard,
//    R4-R6 corruption; ds_read queue vs LDS-DMA are unordered in HW).
//  - consume(h=1): vmcnt(8) drains buf1, next-site buf0 stays in flight.
//  - site barrier: lgkmcnt(0) + raw s_barrier ONLY (v-exchange is pure
//    LDS; wave-private buffers need no barrier). Also covers buf1 re-DMA
//    next site (its ds_reads drained by the barrier's lgkm).
// Frag layouts (R7/R9-verified): A[m=lane&15][k=q4*8+j],
// B^T[n=lane&15][k=q4*8+j], C[row=q4*4+r][col=lane&15]. Chunk LDS
// [p][c16][kseg8] 16B units, kseg slot ^= (c&7); inverse swizzle baked
// into the global staging address.
//
// Fused combine: u/w stored fp16 via agent-scope (LLC-coherent) atomic
// stores; Dekker handshake (seq_cst store own flag, seq_cst load partner)
// -> at least one block of each pair sees the other and computes the dots
// (both-see => benign duplicate identical writes). Init-state agnostic.
// ---------------------------------------------------------------------------
__global__ __launch_bounds__(512, 1) void mps_half_chain(
    const int* __restrict__ onstate, const _Float16* __restrict__ mtf,
    const _Float16* __restrict__ mtb, const float* __restrict__ left_vec,
    const float* __restrict__ right_vec, _Float16* __restrict__ ut,
    _Float16* __restrict__ wt, unsigned* __restrict__ flags,
    float* __restrict__ out) {
  extern __shared__ char smem[];
  const int tid = threadIdx.x;
  const int wave = tid >> 6, lane = tid & 63;
  const int me = lane & 15, q4 = lane >> 4;
  const bool fwd = !(blockIdx.x & 1);
  const int grp = blockIdx.x >> 1;
  const int b0 = grp * EPW;
  const _Float16* mbase = fwd ? mtf : mtb;   // my half's 128 matrices
  const float* ivec = fwd ? left_vec : right_vec;
  _Float16* ovec = fwd ? ut : wt;

  // ---- stage onstate -> plds[site][e] (global site index)
  int* plds = (int*)(smem + PLDS);
#pragma unroll
  for (int j = 0; j < 2; ++j) {
    int idx = tid + j * 512;
    int e = idx >> 6, i = idx & 63;
    plds[i * EPW + e] = onstate[(b0 + e) * L + i];
  }
  // ---- init v = ivec for every element (swizzled fp16)
  if (tid < 256) {
    int e = tid >> 4, seg = tid & 15;
    _Float16* vp = (_Float16*)(smem + VLDS0) + e * 128 + (seg ^ (e & 7)) * 8;
#pragma unroll
    for (int j = 0; j < 8; ++j) vp[j] = (_Float16)ivec[seg * 8 + j];
  }

  char* wbuf = smem + wave * 16384;   // my private 2 x 8 KB chunk buffers

  // per-lane, site-invariant staging source offsets (inverse swizzle baked)
  int soff[8];
#pragma unroll
  for (int i = 0; i < 8; ++i) {
    int u = i * 64 + lane;
    int p = u >> 7, r = u & 127, cl = r >> 3, slot = r & 7;
    soff[i] = p * 32768 + (wave * 16 + cl) * 256 + (slot ^ (cl & 7)) * 16;
  }
  auto stage = [&](int ls, int h, int z) {
    const char* gb = (const char*)mbase + (size_t)ls * 131072 + h * 128;
    char* lb = wbuf + z * 8192;
#pragma unroll
    for (int i = 0; i < 8; ++i) gl2lds16(gb + soff[i], lb + i * 1024);
  };
  auto consume = [&](int h, int z, int pm, const char* vb, v4f& acc) {
    const int s0 = h * 8 + q4, s1 = h * 8 + 4 + q4;
    v8h a0 = *(const v8h*)(vb + me * 256 + (s0 ^ (me & 7)) * 16);
    v8h a1 = *(const v8h*)(vb + me * 256 + (s1 ^ (me & 7)) * 16);
    const char* cb = wbuf + z * 8192;
#pragma unroll
    for (int p = 0; p < P; ++p) {
      const bool isp = (pm == p);
      v8h zf = {};
      v8h am0 = isp ? a0 : zf;
      v8h am1 = isp ? a1 : zf;
      const char* pb = cb + p * 2048 + me * 128;
      v8h bf0 = *(const v8h*)(pb + ((q4) ^ (me & 7)) * 16);
      v8h bf1 = *(const v8h*)(pb + ((4 + q4) ^ (me & 7)) * 16);
      acc = __builtin_amdgcn_mfma_f32_16x16x32_f16(am0, bf0, acc, 0, 0, 0);
      acc = __builtin_amdgcn_mfma_f32_16x16x32_f16(am1, bf1, acc, 0, 0, 0);
    }
  };

  stage(fwd ? 0 : 31, 0, 0);          // prologue: chunk g=0 -> buf0
  __syncthreads();                    // full drain once (incl. prologue DMA)

  const int c0 = wave * 16 + me;      // my output column
  v4f accL = {0.f, 0.f, 0.f, 0.f};
  for (int site = 0; site < 32; ++site) {
    const int site_g = fwd ? site : 63 - site;   // global site (plds index)
    const int ls     = fwd ? site : 31 - site;   // local site in my half
    const int pm = plds[site_g * EPW + me];
    const char* vb = smem + ((site & 1) ? VLDS1 : VLDS0);
    v4f acc = {0.f, 0.f, 0.f, 0.f};

    // ---- h = 0: issue (ls,h=1)->buf1; vmcnt(8) drains buf0 (the oldest 8:
    //      prev-site prefetch); consume buf0
    stage(ls, 1, 1);
    __builtin_amdgcn_s_waitcnt(WAIT_VM8);
    __builtin_amdgcn_sched_barrier(0);
    consume(0, 0, pm, vb, acc);

    // ---- h = 1
    if (site < 31) {
      const int lsn = fwd ? site + 1 : 30 - site;
      // cross-pipe hazard fence: drain my queued ds_reads of buf0 before
      // DMA-writing buf0 (R4-R6 bug)
      __builtin_amdgcn_sched_barrier(0);
      __builtin_amdgcn_s_waitcnt(WAIT_LGKM0);
      __builtin_amdgcn_sched_barrier(0);
      stage(lsn, 0, 0);                         // prefetch next site -> buf0
      __builtin_amdgcn_s_waitcnt(WAIT_VM8);     // drain buf1 only
      __builtin_amdgcn_sched_barrier(0);
      consume(1, 1, pm, vb, acc);
      // v-exchange: write v_new fp16 (C-layout rows) to the other buffer
      _Float16* vn = (_Float16*)(smem + ((site & 1) ? VLDS0 : VLDS1));
#pragma unroll
      for (int r = 0; r < 4; ++r) {
        int e = q4 * 4 + r;
        vn[e * 128 + ((c0 >> 3) ^ (e & 7)) * 8 + (c0 & 7)] = (_Float16)acc[r];
      }
      // LDS-only site barrier: next-site prefetch stays in flight (the R11
      // change — R9's __syncthreads drained vmcnt(0) here every site)
      __builtin_amdgcn_sched_barrier(0);
      __builtin_amdgcn_s_waitcnt(WAIT_LGKM0);
      __builtin_amdgcn_s_barrier();
      __builtin_amdgcn_sched_barrier(0);
    } else {
      __builtin_amdgcn_s_waitcnt(WAIT_VM0);     // last chunk: full drain
      consume(1, 1, pm, vb, acc);
      accL = acc;
    }
  }

  // ---- epilogue: store half-chain vector fp16 [d][b], agent-scope (LLC)
  {
    union { unsigned long long u64; _Float16 h[4]; } pk;
#pragma unroll
    for (int r = 0; r < 4; ++r) pk.h[r] = (_Float16)accL[r];
    unsigned long long* dst =
        (unsigned long long*)(ovec + c0 * B + b0 + q4 * 4);
    __hip_atomic_store(dst, pk.u64, __ATOMIC_RELAXED,
                       __HIP_MEMORY_SCOPE_AGENT);
  }
  __syncthreads();                    // all waves' stores drained (vmcnt)

  // ---- Dekker handshake: last arriver of the (fwd,bwd) pair combines
  int* decide = (int*)(smem + PLDS);  // reuse plds area
  if (tid == 0) {
    unsigned* myf = flags + grp * 2 + (fwd ? 0 : 1);
    unsigned* pf  = flags + grp * 2 + (fwd ? 1 : 0);
    __hip_atomic_store(myf, FLAG_MAGIC, __ATOMIC_SEQ_CST,
                       __HIP_MEMORY_SCOPE_AGENT);
    unsigned pv = __hip_atomic_load(pf, __ATOMIC_SEQ_CST,
                                    __HIP_MEMORY_SCOPE_AGENT);
    *decide = (pv == FLAG_MAGIC);
  }
  __syncthreads();
  if (*decide) {
    // combine: out[b] = sum_d u[d][b] * w[d][b]; 32 lanes per element
    const unsigned* u32u = (const unsigned*)ut;
    const unsigned* u32w = (const unsigned*)wt;
    const int e = tid >> 5, j = tid & 31;
    const int bb = b0 + e;
    const int pidx = bb >> 1, hi = bb & 1;
    float part = 0.f;
#pragma unroll
    for (int d = j; d < D; d += 32) {
      unsigned pu = __hip_atomic_load(&u32u[d * (B / 2) + pidx],
                                      __ATOMIC_RELAXED,
                                      __HIP_MEMORY_SCOPE_AGENT);
      unsigned pw = __hip_atomic_load(&u32w[d * (B / 2) + pidx],
                                      __ATOMIC_RELAXED,
                                      __HIP_MEMORY_SCOPE_AGENT);
      union { unsigned short s; _Float16 h; } cu, cw;
      cu.s = hi ? (unsigned short)(pu >> 16) : (unsigned short)(pu & 0xffff);
      cw.s = hi ? (unsigned short)(pw >> 16) : (unsigned short)(pw & 0xffff);
      part += (float)cu.h * (float)cw.h;
    }
#pragma unroll
    for (int m = 16; m; m >>= 1) part += __shfl_xor(part, m, 64);
    if (j == 0) out[bb] = part;
  }
}

// ---------------------------------------------------------------------------
extern "C" void kernel_launch(void* const* d_in, const int* in_sizes, int n_in,
                              void* d_out, int out_size, void* d_ws,
                              size_t ws_size, hipStream_t stream) {
  const int*   onstate      = (const int*)d_in[0];
  const float* site_tensors = (const float*)d_in[1];
  const float* left_vec     = (const float*)d_in[2];
  const float* right_vec    = (const float*)d_in[3];
  float*       out          = (float*)d_out;
  char*        ws           = (char*)d_ws;   // needs 10 MB (R9-proven)
  _Float16*    ut           = (_Float16*)(ws + UT_OFF);
  _Float16*    wt           = (_Float16*)(ws + WT_OFF);
  unsigned*    flags        = (unsigned*)(ws + FLG_OFF);
  _Float16*    mtf          = (_Float16*)(ws + MTF_OFF);
  _Float16*    mtb          = (_Float16*)(ws + MTB_OFF);

  hipFuncSetAttribute((const void*)mps_half_chain,
                      hipFuncAttributeMaxDynamicSharedMemorySize, SMEM_BYTES);

  convert_dual<<<L * P, 256, 0, stream>>>(site_tensors, mtf, mtb);
  mps_half_chain<<<2 * NG, 512, SMEM_BYTES, stream>>>(
      onstate, mtf, mtb, left_vec, right_vec, ut, wt, flags, out);
}